// Round 4
// baseline (152.078 us; speedup 1.0000x reference)
//
#include <hip/hip_runtime.h>

// Shapes fixed by the reference: B=4, N=M=384, D=256.
#define DD 256
#define NN 384
#define BB 4
#define BN (BB * NN)         // 1536
#define MSPLIT 4
#define MCHUNK (NN / MSPLIT) // 96
#define PSTRIDE (BN * DD)    // one partial plane

// tanh(s) = 1 - 2/(exp2(2*log2e*s)+1). K pre-scaled by 2*log2e; mask adds
// -1e9*2log2e in the exp2 domain -> E=0 -> rcp(1)=1 -> contribution -v exact.
constexpr float TWO_LOG2E = 2.8853900817779268f;
constexpr float MASK_X    = -1.0e9f * 2.8853900817779268f;

// ---------------------------------------------------------------------------
// Projections. grid (BN/8, 3), block 256 = 4 waves, 8 rows/block, k-split:
// wave w owns k in [64w, 64w+64). X staged in LDS TRANSPOSED [k][r] so per k
// two broadcast ds_read_b128 give all 8 rows. W read coalesced dwordx4 with
// 4-deep register prefetch (R3's scalar-load version serialized on
// lgkmcnt(0): SMEM returns out-of-order -> 9% VALUBusy). Partials via LDS.
// ---------------------------------------------------------------------------
__global__ __launch_bounds__(256) void proj_kernel(
    const float* __restrict__ q,  const float* __restrict__ k,  const float* __restrict__ v,
    const float* __restrict__ Wq, const float* __restrict__ Wk, const float* __restrict__ Wv,
    const float* __restrict__ bq, const float* __restrict__ bk, const float* __restrict__ bv,
    float* __restrict__ Qout, float* __restrict__ KVout)
{
    const int tid  = threadIdx.x;
    const int lane = tid & 63;
    const int wv   = tid >> 6;          // k-slice 0..3
    const int row0 = blockIdx.x * 8;
    const int which = blockIdx.y;

    const float* X; const float* W; const float* bias; float scale; float* out; int ostride;
    if (which == 0)      { X = q; W = Wq; bias = bq; scale = 1.0f;      out = Qout;      ostride = 1; }
    else if (which == 1) { X = k; W = Wk; bias = bk; scale = TWO_LOG2E; out = KVout;     ostride = 2; }
    else                 { X = v; W = Wv; bias = bv; scale = 1.0f;      out = KVout + 1; ostride = 2; }

    __shared__ float xs[DD][8];         // [k][r] transposed, 8 KB
    __shared__ float ps[4][8][DD];      // k-slice partials, 32 KB

    const float* Xb = X + (size_t)row0 * DD;
    for (int e = tid; e < 8 * DD; e += 256) {   // e = r*256 + kk, coalesced read
        const int r  = e >> 8;
        const int kk = e & 255;
        xs[kk][r] = Xb[e];
    }
    __syncthreads();

    const int k0 = wv * 64;
    const float* Wp = W + (size_t)k0 * DD + lane * 4;

    float4 acc[8];
    #pragma unroll
    for (int r = 0; r < 8; ++r) acc[r] = make_float4(0.f, 0.f, 0.f, 0.f);

    float4 wbuf[4];
    #pragma unroll
    for (int i = 0; i < 4; ++i) wbuf[i] = *reinterpret_cast<const float4*>(Wp + (size_t)i * DD);

    #pragma unroll 4
    for (int kk = 0; kk < 60; ++kk) {
        const float4 w4 = wbuf[kk & 3];
        wbuf[kk & 3] = *reinterpret_cast<const float4*>(Wp + (size_t)(kk + 4) * DD);
        const float4 xa = *reinterpret_cast<const float4*>(&xs[k0 + kk][0]); // broadcast
        const float4 xb = *reinterpret_cast<const float4*>(&xs[k0 + kk][4]);
        const float xr[8] = {xa.x, xa.y, xa.z, xa.w, xb.x, xb.y, xb.z, xb.w};
        #pragma unroll
        for (int r = 0; r < 8; ++r) {
            acc[r].x = fmaf(xr[r], w4.x, acc[r].x);
            acc[r].y = fmaf(xr[r], w4.y, acc[r].y);
            acc[r].z = fmaf(xr[r], w4.z, acc[r].z);
            acc[r].w = fmaf(xr[r], w4.w, acc[r].w);
        }
    }
    #pragma unroll
    for (int kk = 60; kk < 64; ++kk) {          // drain
        const float4 w4 = wbuf[kk & 3];
        const float4 xa = *reinterpret_cast<const float4*>(&xs[k0 + kk][0]);
        const float4 xb = *reinterpret_cast<const float4*>(&xs[k0 + kk][4]);
        const float xr[8] = {xa.x, xa.y, xa.z, xa.w, xb.x, xb.y, xb.z, xb.w};
        #pragma unroll
        for (int r = 0; r < 8; ++r) {
            acc[r].x = fmaf(xr[r], w4.x, acc[r].x);
            acc[r].y = fmaf(xr[r], w4.y, acc[r].y);
            acc[r].z = fmaf(xr[r], w4.z, acc[r].z);
            acc[r].w = fmaf(xr[r], w4.w, acc[r].w);
        }
    }

    #pragma unroll
    for (int r = 0; r < 8; ++r)
        *reinterpret_cast<float4*>(&ps[wv][r][lane * 4]) = acc[r];
    __syncthreads();

    for (int e = tid; e < 8 * DD; e += 256) {
        const int r = e >> 8;
        const int d = e & 255;
        const float s = (ps[0][r][d] + ps[1][r][d]) + (ps[2][r][d] + ps[3][r][d]);
        out[((size_t)(row0 + r) * DD + d) * ostride] = (s + bias[d]) * scale;
    }
}

// ---------------------------------------------------------------------------
// Fused tanh-contraction. grid (NN/4, BB, MSPLIT) = 1536 blocks (6/CU),
// block 256 (tid = d). Straight-line predicated tanh (R3's wave-uniform
// branches fragmented the schedule: 38% VALUBusy). Mask as additive exp2-
// domain floats in LDS [m][4], broadcast b128 per m. KV ping-pong double-
// buffered 8 float2 per side. Sum(v) hoisted (j-independent).
// ---------------------------------------------------------------------------
__global__ __launch_bounds__(256, 6) void mhsa_kernel(
    const float* __restrict__ Q, const float* __restrict__ KV,
    const int* __restrict__ mask, float* __restrict__ outp)
{
    const int tid = threadIdx.x;         // d
    const int b   = blockIdx.y;
    const int n0  = blockIdx.x * 4;
    const int m0  = blockIdx.z * MCHUNK;

    __shared__ float mf[MCHUNK][4];      // 1.5 KB
    for (int idx = tid; idx < MCHUNK * 4; idx += 256) {
        const int m = idx % MCHUNK;      // consecutive tid -> consecutive m (coalesced)
        const int j = idx / MCHUNK;
        mf[m][j] = mask[(size_t)(b * NN + n0 + j) * NN + (m0 + m)] ? MASK_X : 0.0f;
    }
    __syncthreads();

    float qv[4];
    #pragma unroll
    for (int j = 0; j < 4; ++j)
        qv[j] = Q[(size_t)(b * NN + n0 + j) * DD + tid];

    const float2* kvp = reinterpret_cast<const float2*>(KV)
                      + (size_t)b * NN * DD + (size_t)m0 * DD + tid;

    float acc[4] = {0.f, 0.f, 0.f, 0.f};
    float vsum = 0.f;

#define PROJ_COMPUTE(MLOC, KVV)                                          \
    {                                                                    \
        const float4 m4 = *reinterpret_cast<const float4*>(&mf[MLOC][0]);\
        const float kk = (KVV).x, vv = (KVV).y;                          \
        const float t2 = -2.0f * vv;                                     \
        vsum += vv;                                                      \
        const float mm[4] = {m4.x, m4.y, m4.z, m4.w};                    \
        _Pragma("unroll")                                                \
        for (int j = 0; j < 4; ++j) {                                    \
            const float x = fmaf(qv[j], kk, mm[j]);                      \
            const float E = __builtin_amdgcn_exp2f(x);                   \
            const float r = __builtin_amdgcn_rcpf(E + 1.0f);             \
            acc[j] = fmaf(t2, r, acc[j]);                                \
        }                                                                \
    }

    float2 bufA[8], bufB[8];
    #pragma unroll
    for (int u = 0; u < 8; ++u)
        bufA[u] = kvp[(size_t)u * DD];

    for (int mg = 0; mg < MCHUNK; mg += 16) {
        #pragma unroll
        for (int u = 0; u < 8; ++u)
            bufB[u] = kvp[(size_t)(mg + 8 + u) * DD];   // prefetch group B
        #pragma unroll
        for (int u = 0; u < 8; ++u)
            PROJ_COMPUTE(mg + u, bufA[u]);              // compute group A
        if (mg + 16 < MCHUNK) {
            #pragma unroll
            for (int u = 0; u < 8; ++u)
                bufA[u] = kvp[(size_t)(mg + 16 + u) * DD]; // prefetch next A
        }
        #pragma unroll
        for (int u = 0; u < 8; ++u)
            PROJ_COMPUTE(mg + 8 + u, bufB[u]);          // compute group B
    }
#undef PROJ_COMPUTE

    float* po = outp + (size_t)blockIdx.z * PSTRIDE;
    #pragma unroll
    for (int j = 0; j < 4; ++j)
        po[(size_t)(b * NN + n0 + j) * DD + tid] = acc[j] + vsum;
}

// Sum the MSPLIT partial planes. grid BN*DD/256 = 1536 blocks.
__global__ __launch_bounds__(256) void reduce4_kernel(
    const float* __restrict__ part, float* __restrict__ out)
{
    const int i = blockIdx.x * 256 + threadIdx.x;
    out[i] = (part[i] + part[i + PSTRIDE])
           + (part[i + 2 * PSTRIDE] + part[i + 3 * PSTRIDE]);
}

extern "C" void kernel_launch(void* const* d_in, const int* in_sizes, int n_in,
                              void* d_out, int out_size, void* d_ws, size_t ws_size,
                              hipStream_t stream) {
    const float* q    = (const float*)d_in[0];
    const float* k    = (const float*)d_in[1];
    const float* v    = (const float*)d_in[2];
    const int*   mask = (const int*)  d_in[3];
    const float* Wq   = (const float*)d_in[4];
    const float* bq   = (const float*)d_in[5];
    const float* Wk   = (const float*)d_in[6];
    const float* bk   = (const float*)d_in[7];
    const float* Wv   = (const float*)d_in[8];
    const float* bv   = (const float*)d_in[9];
    float* out = (float*)d_out;

    float* Qws   = (float*)d_ws;                 // BN*DD floats      (1.57 MB)
    float* KVws  = Qws  + (size_t)BN * DD;       // BN*DD float2s     (3.15 MB)
    float* Pws   = KVws + (size_t)2 * BN * DD;   // MSPLIT planes     (6.29 MB)

    dim3 g1(BN / 8, 3);
    proj_kernel<<<g1, 256, 0, stream>>>(q, k, v, Wq, Wk, Wv, bq, bk, bv, Qws, KVws);

    dim3 g2(NN / 4, BB, MSPLIT);
    mhsa_kernel<<<g2, 256, 0, stream>>>(Qws, KVws, mask, Pws);

    reduce4_kernel<<<dim3(BN * DD / 256), 256, 0, stream>>>(Pws, out);
}

// Round 5
// 129.459 us; speedup vs baseline: 1.1747x; 1.1747x over previous
//
#include <hip/hip_runtime.h>

// Shapes fixed by the reference: B=4, N=M=384, D=256.
#define DD 256
#define NN 384
#define BB 4
#define BN (BB * NN)         // 1536
#define MSPLIT 4
#define MCHUNK (NN / MSPLIT) // 96
#define PSTRIDE (BN * DD)    // one partial plane

// tanh(s) = 1 - 2/(exp2(2*log2e*s)+1). K pre-scaled by 2*log2e; mask adds
// -1e9*2log2e in the exp2 domain -> E=0 -> rcp(1)=1 -> contribution -v exact.
constexpr float TWO_LOG2E = 2.8853900817779268f;
constexpr float MASK_X    = -1.0e9f * 2.8853900817779268f;

// ---------------------------------------------------------------------------
// Projections. grid (BN/8, 3), block 256 = 4 waves, 8 rows/block; wave wv
// owns k in [64wv, 64wv+64), lane owns d = lane*4..+3 (float4 acc per row).
// x values are wave-uniform -> VMEM BROADCAST float4 loads from global (all
// lanes same addr = 1 L1 transaction, in-order vmcnt; R3's s_load version
// serialized on out-of-order lgkmcnt). No staging LDS, no staging barrier.
// Cross-wave k-reduce through 32 KB ps at the end.
// ---------------------------------------------------------------------------
__global__ __launch_bounds__(256) void proj_kernel(
    const float* __restrict__ q,  const float* __restrict__ k,  const float* __restrict__ v,
    const float* __restrict__ Wq, const float* __restrict__ Wk, const float* __restrict__ Wv,
    const float* __restrict__ bq, const float* __restrict__ bk, const float* __restrict__ bv,
    float* __restrict__ Qout, float* __restrict__ KVout)
{
    const int tid  = threadIdx.x;
    const int lane = tid & 63;
    const int wv   = tid >> 6;          // k-slice 0..3
    const int row0 = blockIdx.x * 8;
    const int which = blockIdx.y;

    const float* X; const float* W; const float* bias; float scale; float* out; int ostride;
    if (which == 0)      { X = q; W = Wq; bias = bq; scale = 1.0f;      out = Qout;      ostride = 1; }
    else if (which == 1) { X = k; W = Wk; bias = bk; scale = TWO_LOG2E; out = KVout;     ostride = 2; }
    else                 { X = v; W = Wv; bias = bv; scale = 1.0f;      out = KVout + 1; ostride = 2; }

    __shared__ float ps[4][8][DD];      // k-slice partials, 32 KB

    const int k0 = wv * 64;
    const float* Xb = X + (size_t)row0 * DD + k0;      // x[row0+r][k0+...]
    const float* Wp = W + (size_t)k0 * DD + lane * 4;  // W[k0+...][lane*4]

    float4 acc[8];
    #pragma unroll
    for (int r = 0; r < 8; ++r) acc[r] = make_float4(0.f, 0.f, 0.f, 0.f);

    #pragma unroll 2
    for (int g = 0; g < 16; ++g) {      // 4 k's per group
        float4 xq[8];
        #pragma unroll
        for (int r = 0; r < 8; ++r)     // broadcast: all lanes same address
            xq[r] = *reinterpret_cast<const float4*>(Xb + r * DD + g * 4);
        float4 wq[4];
        #pragma unroll
        for (int u = 0; u < 4; ++u)     // coalesced 1 KB/wave
            wq[u] = *reinterpret_cast<const float4*>(Wp + (size_t)(g * 4 + u) * DD);
        #pragma unroll
        for (int u = 0; u < 4; ++u) {
            const float4 w = wq[u];
            #pragma unroll
            for (int r = 0; r < 8; ++r) {
                const float x = (u == 0) ? xq[r].x : (u == 1) ? xq[r].y
                              : (u == 2) ? xq[r].z : xq[r].w;   // resolved at compile time
                acc[r].x = fmaf(x, w.x, acc[r].x);
                acc[r].y = fmaf(x, w.y, acc[r].y);
                acc[r].z = fmaf(x, w.z, acc[r].z);
                acc[r].w = fmaf(x, w.w, acc[r].w);
            }
        }
    }

    #pragma unroll
    for (int r = 0; r < 8; ++r)
        *reinterpret_cast<float4*>(&ps[wv][r][lane * 4]) = acc[r];
    __syncthreads();

    for (int e = tid; e < 8 * DD; e += 256) {
        const int r = e >> 8;
        const int d = e & 255;
        const float s = (ps[0][r][d] + ps[1][r][d]) + (ps[2][r][d] + ps[3][r][d]);
        out[((size_t)(row0 + r) * DD + d) * ostride] = (s + bias[d]) * scale;
    }
}

// ---------------------------------------------------------------------------
// Fused tanh-contraction. grid (NN/4, BB, MSPLIT) = 1536 blocks (6/CU),
// block 256 (tid = d). NAMED float2 double-buffers (R4's buffer ARRAYS with a
// conditional refill were demoted to scratch: 149 MB spill writes). Refills
// beyond m=96 overread harmlessly into the adjacent ws region (values unused).
// Straight-line predicated tanh; mask as additive exp2-domain floats in LDS.
// ---------------------------------------------------------------------------
__global__ __launch_bounds__(256) void mhsa_kernel(
    const float* __restrict__ Q, const float* __restrict__ KV,
    const int* __restrict__ mask, float* __restrict__ outp)
{
    const int tid = threadIdx.x;         // d
    const int b   = blockIdx.y;
    const int n0  = blockIdx.x * 4;
    const int m0  = blockIdx.z * MCHUNK;

    __shared__ float mf[MCHUNK][4];      // 1.5 KB
    for (int idx = tid; idx < MCHUNK * 4; idx += 256) {
        const int m = idx % MCHUNK;      // consecutive tid -> consecutive m (coalesced)
        const int j = idx / MCHUNK;
        mf[m][j] = mask[(size_t)(b * NN + n0 + j) * NN + (m0 + m)] ? MASK_X : 0.0f;
    }
    __syncthreads();

    float qv0 = Q[(size_t)(b * NN + n0 + 0) * DD + tid];
    float qv1 = Q[(size_t)(b * NN + n0 + 1) * DD + tid];
    float qv2 = Q[(size_t)(b * NN + n0 + 2) * DD + tid];
    float qv3 = Q[(size_t)(b * NN + n0 + 3) * DD + tid];

    const float2* kvp = reinterpret_cast<const float2*>(KV)
                      + (size_t)b * NN * DD + (size_t)m0 * DD + tid;

    float acc0 = 0.f, acc1 = 0.f, acc2 = 0.f, acc3 = 0.f, vsum = 0.f;

// one m: 4 rows of tanh, fully unrolled, no local arrays
#define COMP(KVV, MLOC)                                                       \
    {                                                                         \
        const float4 m4 = *reinterpret_cast<const float4*>(&mf[MLOC][0]);     \
        const float kk = (KVV).x, vv = (KVV).y;                               \
        const float t2 = -2.0f * vv;                                          \
        vsum += vv;                                                           \
        const float x0 = fmaf(qv0, kk, m4.x);                                 \
        const float x1 = fmaf(qv1, kk, m4.y);                                 \
        const float x2 = fmaf(qv2, kk, m4.z);                                 \
        const float x3 = fmaf(qv3, kk, m4.w);                                 \
        acc0 = fmaf(t2, __builtin_amdgcn_rcpf(__builtin_amdgcn_exp2f(x0) + 1.0f), acc0); \
        acc1 = fmaf(t2, __builtin_amdgcn_rcpf(__builtin_amdgcn_exp2f(x1) + 1.0f), acc1); \
        acc2 = fmaf(t2, __builtin_amdgcn_rcpf(__builtin_amdgcn_exp2f(x2) + 1.0f), acc2); \
        acc3 = fmaf(t2, __builtin_amdgcn_rcpf(__builtin_amdgcn_exp2f(x3) + 1.0f), acc3); \
    }

#define LOADG(B0, B1, B2, B3, M0)                \
    B0 = kvp[(size_t)((M0) + 0) * DD];           \
    B1 = kvp[(size_t)((M0) + 1) * DD];           \
    B2 = kvp[(size_t)((M0) + 2) * DD];           \
    B3 = kvp[(size_t)((M0) + 3) * DD];

    float2 A0, A1, A2, A3, B0, B1, B2, B3;
    LOADG(A0, A1, A2, A3, 0)
    LOADG(B0, B1, B2, B3, 4)

    for (int mg = 0; mg < MCHUNK; mg += 8) {
        COMP(A0, mg + 0) COMP(A1, mg + 1) COMP(A2, mg + 2) COMP(A3, mg + 3)
        LOADG(A0, A1, A2, A3, mg + 8)    // mg=88 -> m 96..99: harmless overread
        COMP(B0, mg + 4) COMP(B1, mg + 5) COMP(B2, mg + 6) COMP(B3, mg + 7)
        LOADG(B0, B1, B2, B3, mg + 12)   // mg=88 -> m 100..103: harmless overread
    }
#undef COMP
#undef LOADG

    float* po = outp + (size_t)blockIdx.z * PSTRIDE;
    po[(size_t)(b * NN + n0 + 0) * DD + tid] = acc0 + vsum;
    po[(size_t)(b * NN + n0 + 1) * DD + tid] = acc1 + vsum;
    po[(size_t)(b * NN + n0 + 2) * DD + tid] = acc2 + vsum;
    po[(size_t)(b * NN + n0 + 3) * DD + tid] = acc3 + vsum;
}

// Sum the MSPLIT partial planes. grid BN*DD/256 = 1536 blocks.
__global__ __launch_bounds__(256) void reduce4_kernel(
    const float* __restrict__ part, float* __restrict__ out)
{
    const int i = blockIdx.x * 256 + threadIdx.x;
    out[i] = (part[i] + part[i + PSTRIDE])
           + (part[i + 2 * PSTRIDE] + part[i + 3 * PSTRIDE]);
}

extern "C" void kernel_launch(void* const* d_in, const int* in_sizes, int n_in,
                              void* d_out, int out_size, void* d_ws, size_t ws_size,
                              hipStream_t stream) {
    const float* q    = (const float*)d_in[0];
    const float* k    = (const float*)d_in[1];
    const float* v    = (const float*)d_in[2];
    const int*   mask = (const int*)  d_in[3];
    const float* Wq   = (const float*)d_in[4];
    const float* bq   = (const float*)d_in[5];
    const float* Wk   = (const float*)d_in[6];
    const float* bk   = (const float*)d_in[7];
    const float* Wv   = (const float*)d_in[8];
    const float* bv   = (const float*)d_in[9];
    float* out = (float*)d_out;

    float* Qws   = (float*)d_ws;                 // BN*DD floats      (1.57 MB)
    float* KVws  = Qws  + (size_t)BN * DD;       // BN*DD float2s     (3.15 MB)
    float* Pws   = KVws + (size_t)2 * BN * DD;   // MSPLIT planes     (6.29 MB)
                                                 // (KV overread spills into Pws: safe)

    dim3 g1(BN / 8, 3);
    proj_kernel<<<g1, 256, 0, stream>>>(q, k, v, Wq, Wk, Wv, bq, bk, bv, Qws, KVws);

    dim3 g2(NN / 4, BB, MSPLIT);
    mhsa_kernel<<<g2, 256, 0, stream>>>(Qws, KVws, mask, Pws);

    reduce4_kernel<<<dim3(BN * DD / 256), 256, 0, stream>>>(Pws, out);
}